// Round 2
// baseline (578.970 us; speedup 1.0000x reference)
//
#include <hip/hip_runtime.h>
#include <math.h>

#define NUM_K 128
#define DIM   256
#define KT    64              // code tile per pass (2 passes over X, 2nd hits L2)
#define NROWS (64 * 2048)     // 131072
#define BLOCK 256
#define GRID  (NROWS / BLOCK) // 512

// flat fp32 output offsets (reference tuple order)
#define OFF_LOSS 0u
#define OFF_Q    1u
#define OFF_PERP 33554433u
#define OFF_ENC  33554434u
#define OFF_IDX  50331650u

// ws float layout: [0] loss accumulator; ints at float-idx [64..191] counts; [256..383] se[k]

__global__ void vq_setup(const float* __restrict__ E, float* __restrict__ ws) {
    int t = threadIdx.x;            // 128 threads
    if (t == 0) ws[0] = 0.0f;
    ((int*)ws)[64 + t] = 0;
    float s = 0.0f;
    for (int d = 0; d < DIM; ++d) { float v = E[t * DIM + d]; s += v * v; }
    ws[256 + t] = s;
}

// 4 waves/EU min -> VGPR cap 128; acc[64]+xr[16]+addr ~= 100 VGPR, no spill.
__global__ __launch_bounds__(BLOCK, 4) void vq_main(
        const float* __restrict__ X, const float* __restrict__ E,
        float* ws, float* __restrict__ out) {
    const int tid = threadIdx.x;
    const int row = blockIdx.x * BLOCK + tid;
    const float* xrow = X + (size_t)row * DIM;

    float dmin = INFINITY; int idx = 0; float sx = 0.0f;

    for (int half = 0; half < 2; ++half) {
        const int kb = half * KT;
        float acc[KT];
        #pragma unroll
        for (int k = 0; k < KT; ++k) acc[k] = 0.0f;

        for (int dc = 0; dc < DIM; dc += 16) {
            float xr[16];
            #pragma unroll
            for (int j = 0; j < 4; ++j) {
                float4 v = *(const float4*)(xrow + dc + 4 * j);
                xr[4*j+0] = v.x; xr[4*j+1] = v.y; xr[4*j+2] = v.z; xr[4*j+3] = v.w;
            }
            if (half == 0) {
                #pragma unroll
                for (int j = 0; j < 16; ++j) sx = fmaf(xr[j], xr[j], sx);
            }
            #pragma unroll
            for (int k = 0; k < KT; ++k) {
                // (kb+k), dc are uniform -> wave-uniform address -> s_load path
                const float* erow = E + (size_t)(kb + k) * DIM + dc;
                float s = 0.0f;
                #pragma unroll
                for (int j = 0; j < 16; ++j) s = fmaf(xr[j], erow[j], s);
                acc[k] += s;
            }
        }

        // running argmin over t_k = ||e_k||^2 - 2 x.e_k  (||x||^2 shift is order-free)
        #pragma unroll
        for (int k = 0; k < KT; ++k) {
            float t = ws[256 + kb + k] - 2.0f * acc[k];
            if (t < dmin) { dmin = t; idx = kb + k; }  // strict <: first-index ties (np)
        }
    }

    out[OFF_IDX + row] = (float)idx;

    // loss partial: ||x - e_idx||^2 = sx + dmin ; wave-reduce then one atomic per wave
    float v = sx + dmin;
    #pragma unroll
    for (int off = 32; off; off >>= 1) v += __shfl_down(v, off);
    if ((tid & 63) == 0) atomicAdd(&ws[0], v);

    __shared__ int idxs[BLOCK];
    __shared__ int hcnt[NUM_K];
    if (tid < NUM_K) hcnt[tid] = 0;
    idxs[tid] = idx;
    __syncthreads();
    atomicAdd(&hcnt[idx], 1);
    __syncthreads();
    if (tid < NUM_K) atomicAdd((int*)ws + 64 + tid, hcnt[tid]);

    // ---- write phase (coalesced) ----
    const int r0 = blockIdx.x * BLOCK;
    const int lane = tid & 63;
    const int sub  = tid >> 6;          // 0..3

    // quantized: 4 rows per iteration, scalar dword stores (OFF_Q=1 breaks 16B align)
    for (int rb = 0; rb < BLOCK; rb += 4) {
        int r = rb + sub;
        const float* erow = E + (size_t)idxs[r] * DIM;
        size_t base = OFF_Q + (size_t)(r0 + r) * DIM;
        #pragma unroll
        for (int j = 0; j < 4; ++j)
            out[base + lane + 64 * j] = erow[lane + 64 * j];
    }

    // encodings one-hot: float2 stores (OFF_ENC even -> 8B aligned)
    for (int rb = 0; rb < BLOCK; rb += 4) {
        int r = rb + sub;
        int ir = idxs[r];
        int kp = lane * 2;
        float2 e2;
        e2.x = (kp     == ir) ? 1.0f : 0.0f;
        e2.y = (kp + 1 == ir) ? 1.0f : 0.0f;
        *(float2*)(out + OFF_ENC + (size_t)(r0 + r) * NUM_K + kp) = e2;
    }
}

__global__ void vq_final(const float* __restrict__ ws, float* __restrict__ out) {
    int t = threadIdx.x;   // 128 threads
    if (t == 0) out[OFF_LOSS] = 0.25f * (ws[0] / (float)((size_t)NROWS * DIM));
    int c = ((const int*)ws)[64 + t];
    float p = (float)c / (float)NROWS;
    float v = p * logf(p + 1e-10f);
    #pragma unroll
    for (int off = 32; off; off >>= 1) v += __shfl_down(v, off);
    __shared__ float red[2];
    if ((t & 63) == 0) red[t >> 6] = v;
    __syncthreads();
    if (t == 0) out[OFF_PERP] = expf(-(red[0] + red[1]));
}

extern "C" void kernel_launch(void* const* d_in, const int* in_sizes, int n_in,
                              void* d_out, int out_size, void* d_ws, size_t ws_size,
                              hipStream_t stream) {
    const float* X = (const float*)d_in[0];   // [64,2048,256] fp32
    const float* E = (const float*)d_in[1];   // [128,256] fp32
    float* out = (float*)d_out;
    float* ws  = (float*)d_ws;                // needs >= 1536 bytes

    vq_setup<<<1, 128, 0, stream>>>(E, ws);
    vq_main <<<GRID, BLOCK, 0, stream>>>(X, E, ws, out);
    vq_final<<<1, 128, 0, stream>>>(ws, out);
}

// Round 3
// 405.116 us; speedup vs baseline: 1.4291x; 1.4291x over previous
//
#include <hip/hip_runtime.h>
#include <math.h>

#define NUM_K 128
#define DIM   256
#define NROWS (64 * 2048)       // 131072
#define BLOCK 256
#define ROWS_PER_BLOCK 64
#define GRID  (NROWS / ROWS_PER_BLOCK)  // 2048
#define KPT   32                // codes per thread (4 wave-groups x 32 = 128)

// flat fp32 output offsets (reference tuple order)
#define OFF_LOSS 0u
#define OFF_Q    1u
#define OFF_PERP 33554433u
#define OFF_ENC  33554434u
#define OFF_IDX  50331650u

// ws float layout: [0] loss acc; ints at float-idx [64..191] counts; floats [256..383] se[k]

// 128 blocks x 64 lanes: block k computes ||e_k||^2; block 0 zeroes accumulators.
__global__ void vq_init(const float* __restrict__ E, float* __restrict__ ws) {
    int k = blockIdx.x, lane = threadIdx.x;
    float4 v = *(const float4*)(E + (size_t)k * DIM + lane * 4);
    float s = v.x * v.x + v.y * v.y + v.z * v.z + v.w * v.w;
    #pragma unroll
    for (int off = 32; off; off >>= 1) s += __shfl_down(s, off);
    if (lane == 0) ws[256 + k] = s;
    if (k == 0) {
        if (lane == 0) ws[0] = 0.0f;
        ((int*)ws)[64 + lane]  = 0;
        ((int*)ws)[128 + lane] = 0;
    }
}

// 2048 blocks x 256 threads. Thread (kg=tid>>6, lane=tid&63): row = blk*64+lane,
// codes [kg*32, kg*32+32). kg is wave-uniform -> readfirstlane -> E stays on s_load path.
__global__ __launch_bounds__(BLOCK, 6) void vq_main(
        const float* __restrict__ X, const float* __restrict__ E,
        float* ws, float* __restrict__ out) {
    const int tid  = threadIdx.x;
    const int lane = tid & 63;
    const int kg   = __builtin_amdgcn_readfirstlane(tid >> 6);   // 0..3, wave-uniform
    const int r0   = blockIdx.x * ROWS_PER_BLOCK;
    const int row  = r0 + lane;
    const float* xrow = X + (size_t)row * DIM;
    const float* Eb   = E + (size_t)kg * KPT * DIM;              // uniform base -> s_load

    float acc[KPT];
    #pragma unroll
    for (int k = 0; k < KPT; ++k) acc[k] = 0.0f;
    float sx = 0.0f;

    for (int dc = 0; dc < DIM; dc += 8) {
        float4 v0 = *(const float4*)(xrow + dc);
        float4 v1 = *(const float4*)(xrow + dc + 4);
        float xr[8] = {v0.x, v0.y, v0.z, v0.w, v1.x, v1.y, v1.z, v1.w};
        if (kg == 0) {      // wave-uniform branch; only wave 0 needs ||x||^2
            #pragma unroll
            for (int j = 0; j < 8; ++j) sx = fmaf(xr[j], xr[j], sx);
        }
        #pragma unroll
        for (int k = 0; k < KPT; ++k) {
            const float* er = Eb + k * DIM + dc;   // uniform addr, imm offsets
            float s = 0.0f;
            #pragma unroll
            for (int j = 0; j < 8; ++j) s = fmaf(xr[j], er[j], s);
            acc[k] += s;
        }
    }

    // per-thread argmin over its 32 codes: t_k = ||e_k||^2 - 2 x.e_k
    const float* se = ws + 256 + kg * KPT;   // uniform -> s_load
    float dmin = INFINITY; int idx = kg * KPT;
    #pragma unroll
    for (int k = 0; k < KPT; ++k) {
        float t = se[k] - 2.0f * acc[k];
        if (t < dmin) { dmin = t; idx = kg * KPT + k; }  // strict <: first-index ties
    }

    // cross-group reduce (kg ascending, strict < keeps np first-index semantics)
    __shared__ float rd[4][ROWS_PER_BLOCK];
    __shared__ int   ri[4][ROWS_PER_BLOCK];
    __shared__ float rsx[ROWS_PER_BLOCK];
    __shared__ int   idxs[ROWS_PER_BLOCK];
    __shared__ int   hcnt[NUM_K];
    rd[kg][lane] = dmin;
    ri[kg][lane] = idx;
    if (kg == 0) rsx[lane] = sx;
    if (tid < NUM_K) hcnt[tid] = 0;
    __syncthreads();

    if (kg == 0) {
        float dm = rd[0][lane]; int ix = ri[0][lane];
        #pragma unroll
        for (int g = 1; g < 4; ++g) {
            float t = rd[g][lane];
            if (t < dm) { dm = t; ix = ri[g][lane]; }
        }
        idxs[lane] = ix;
        out[OFF_IDX + row] = (float)ix;
        atomicAdd(&hcnt[ix], 1);
        float v = rsx[lane] + dm;             // ||x - e_ix||^2
        #pragma unroll
        for (int off = 32; off; off >>= 1) v += __shfl_down(v, off);
        if (lane == 0) atomicAdd(&ws[0], v);
    }
    __syncthreads();
    if (tid < NUM_K && hcnt[tid]) atomicAdd((int*)ws + 64 + tid, hcnt[tid]);

    // ---- write phase ----
    // quantized: one row per iteration, 256 threads = 256 cols, coalesced dwords
    for (int r = 0; r < ROWS_PER_BLOCK; ++r) {
        int ix = idxs[r];                      // LDS broadcast
        out[OFF_Q + (size_t)(r0 + r) * DIM + tid] = E[(size_t)ix * DIM + tid];
    }
    // encodings one-hot: 64 rows x 64 float2 = 4096 slots, 16 iterations
    for (int it = 0; it < 16; ++it) {
        int s  = it * BLOCK + tid;
        int r  = s >> 6;
        int kp = (s & 63) * 2;
        int ix = idxs[r];
        float2 e2;
        e2.x = (kp     == ix) ? 1.0f : 0.0f;
        e2.y = (kp + 1 == ix) ? 1.0f : 0.0f;
        *(float2*)(out + OFF_ENC + (size_t)(r0 + r) * NUM_K + kp) = e2;
    }
}

__global__ void vq_final(const float* __restrict__ ws, float* __restrict__ out) {
    int t = threadIdx.x;   // 128 threads
    if (t == 0) out[OFF_LOSS] = 0.25f * (ws[0] / (float)((size_t)NROWS * DIM));
    int c = ((const int*)ws)[64 + t];
    float p = (float)c / (float)NROWS;
    float v = p * logf(p + 1e-10f);
    #pragma unroll
    for (int off = 32; off; off >>= 1) v += __shfl_down(v, off);
    __shared__ float red[2];
    if ((t & 63) == 0) red[t >> 6] = v;
    __syncthreads();
    if (t == 0) out[OFF_PERP] = expf(-(red[0] + red[1]));
}

extern "C" void kernel_launch(void* const* d_in, const int* in_sizes, int n_in,
                              void* d_out, int out_size, void* d_ws, size_t ws_size,
                              hipStream_t stream) {
    const float* X = (const float*)d_in[0];   // [64,2048,256] fp32
    const float* E = (const float*)d_in[1];   // [128,256] fp32
    float* out = (float*)d_out;
    float* ws  = (float*)d_ws;                // needs >= 1536 bytes

    vq_init <<<NUM_K, 64, 0, stream>>>(E, ws);
    vq_main <<<GRID, BLOCK, 0, stream>>>(X, E, ws, out);
    vq_final<<<1, 128, 0, stream>>>(ws, out);
}

// Round 4
// 401.240 us; speedup vs baseline: 1.4430x; 1.0097x over previous
//
#include <hip/hip_runtime.h>
#include <math.h>

#define NUM_K 128
#define DIM   256
#define NROWS (64 * 2048)       // 131072
#define BLOCK 256
#define ROWS_PER_BLOCK 64
#define GRID  (NROWS / ROWS_PER_BLOCK)  // 2048

// flat fp32 output offsets (reference tuple order)
#define OFF_LOSS 0u
#define OFF_Q    1u
#define OFF_PERP 33554433u
#define OFF_ENC  33554434u
#define OFF_IDX  50331650u

// ws float layout: [0] loss acc; ints at float-idx [64..191] counts; floats [256..383] se[k]

// First-class SSA vectors -> guaranteed VGPRs (no alloca, PromoteAlloca can't bail)
typedef float f8v __attribute__((ext_vector_type(8)));

// 128 blocks x 64 lanes: block k computes ||e_k||^2; block 0 zeroes accumulators.
__global__ void vq_init(const float* __restrict__ E, float* __restrict__ ws) {
    int k = blockIdx.x, lane = threadIdx.x;
    float4 v = *(const float4*)(E + (size_t)k * DIM + lane * 4);
    float s = v.x * v.x + v.y * v.y + v.z * v.z + v.w * v.w;
    #pragma unroll
    for (int off = 32; off; off >>= 1) s += __shfl_down(s, off);
    if (lane == 0) ws[256 + k] = s;
    if (k == 0) {
        if (lane == 0) ws[0] = 0.0f;
        ((int*)ws)[64 + lane]  = 0;
        ((int*)ws)[128 + lane] = 0;
    }
}

// 2048 blocks x 256 threads. Thread (kg=tid>>6, lane=tid&63): row = blk*64+lane,
// codes [kg*32, kg*32+32). kg wave-uniform via readfirstlane -> E stays on s_load path.
__global__ __launch_bounds__(BLOCK, 4) void vq_main(
        const float* __restrict__ X, const float* __restrict__ E,
        float* ws, float* __restrict__ out) {
    const int tid  = threadIdx.x;
    const int lane = tid & 63;
    const int kg   = __builtin_amdgcn_readfirstlane(tid >> 6);   // 0..3, wave-uniform
    const int r0   = blockIdx.x * ROWS_PER_BLOCK;
    const int row  = r0 + lane;
    const float* xrow = X + (size_t)row * DIM;
    const float* Eb   = E + (size_t)kg * 32 * DIM;               // uniform base -> s_load

    f8v acc0, acc1, acc2, acc3;   // 32 accumulators, SSA vectors
    #pragma unroll
    for (int k = 0; k < 8; ++k) { acc0[k] = 0.f; acc1[k] = 0.f; acc2[k] = 0.f; acc3[k] = 0.f; }
    float sx = 0.0f;

    for (int dc = 0; dc < DIM; dc += 8) {
        float4 a0 = *(const float4*)(xrow + dc);
        float4 a1 = *(const float4*)(xrow + dc + 4);
        if (kg == 0) {   // wave-uniform branch; only wave 0 needs ||x||^2
            sx = fmaf(a0.x, a0.x, sx); sx = fmaf(a0.y, a0.y, sx);
            sx = fmaf(a0.z, a0.z, sx); sx = fmaf(a0.w, a0.w, sx);
            sx = fmaf(a1.x, a1.x, sx); sx = fmaf(a1.y, a1.y, sx);
            sx = fmaf(a1.z, a1.z, sx); sx = fmaf(a1.w, a1.w, sx);
        }
#define KBODY(AC, KB)                                                     \
        _Pragma("unroll")                                                 \
        for (int k = 0; k < 8; ++k) {                                     \
            const float* er = Eb + (size_t)(KB + k) * DIM + dc;           \
            AC[k] = fmaf(a0.x, er[0], AC[k]);                             \
            AC[k] = fmaf(a0.y, er[1], AC[k]);                             \
            AC[k] = fmaf(a0.z, er[2], AC[k]);                             \
            AC[k] = fmaf(a0.w, er[3], AC[k]);                             \
            AC[k] = fmaf(a1.x, er[4], AC[k]);                             \
            AC[k] = fmaf(a1.y, er[5], AC[k]);                             \
            AC[k] = fmaf(a1.z, er[6], AC[k]);                             \
            AC[k] = fmaf(a1.w, er[7], AC[k]);                             \
        }
        KBODY(acc0, 0)
        KBODY(acc1, 8)
        KBODY(acc2, 16)
        KBODY(acc3, 24)
#undef KBODY
    }

    // per-thread argmin over its 32 codes: t_k = ||e_k||^2 - 2 x.e_k
    const float* se = ws + 256 + kg * 32;    // uniform -> s_load
    float dmin = INFINITY; int idx = kg * 32;
#define AMIN(AC, KB)                                                      \
    _Pragma("unroll")                                                     \
    for (int k = 0; k < 8; ++k) {                                         \
        float t = se[KB + k] - 2.0f * AC[k];                              \
        if (t < dmin) { dmin = t; idx = kg * 32 + KB + k; }               \
    }
    AMIN(acc0, 0) AMIN(acc1, 8) AMIN(acc2, 16) AMIN(acc3, 24)
#undef AMIN

    // cross-group reduce (kg ascending, strict < keeps np first-index semantics)
    __shared__ float rd[4][ROWS_PER_BLOCK];
    __shared__ int   ri[4][ROWS_PER_BLOCK];
    __shared__ float rsx[ROWS_PER_BLOCK];
    __shared__ int   idxs[ROWS_PER_BLOCK];
    __shared__ int   hcnt[NUM_K];
    rd[kg][lane] = dmin;
    ri[kg][lane] = idx;
    if (kg == 0) rsx[lane] = sx;
    if (tid < NUM_K) hcnt[tid] = 0;
    __syncthreads();

    if (kg == 0) {
        float dm = rd[0][lane]; int ix = ri[0][lane];
        #pragma unroll
        for (int g = 1; g < 4; ++g) {
            float t = rd[g][lane];
            if (t < dm) { dm = t; ix = ri[g][lane]; }
        }
        idxs[lane] = ix;
        out[OFF_IDX + row] = (float)ix;
        atomicAdd(&hcnt[ix], 1);
        float v = rsx[lane] + dm;             // ||x - e_ix||^2
        #pragma unroll
        for (int off = 32; off; off >>= 1) v += __shfl_down(v, off);
        if (lane == 0) atomicAdd(&ws[0], v);
    }
    __syncthreads();
    if (tid < NUM_K && hcnt[tid]) atomicAdd((int*)ws + 64 + tid, hcnt[tid]);

    // ---- write phase ----
    // quantized: one row per iteration, 256 threads = 256 cols, coalesced dwords
    for (int r = 0; r < ROWS_PER_BLOCK; ++r) {
        int ix = idxs[r];                      // LDS broadcast
        out[OFF_Q + (size_t)(r0 + r) * DIM + tid] = E[(size_t)ix * DIM + tid];
    }
    // encodings one-hot: 64 rows x 64 float2 = 4096 slots, 16 iterations
    for (int it = 0; it < 16; ++it) {
        int s  = it * BLOCK + tid;
        int r  = s >> 6;
        int kp = (s & 63) * 2;
        int ix = idxs[r];
        float2 e2;
        e2.x = (kp     == ix) ? 1.0f : 0.0f;
        e2.y = (kp + 1 == ix) ? 1.0f : 0.0f;
        *(float2*)(out + OFF_ENC + (size_t)(r0 + r) * NUM_K + kp) = e2;
    }
}

__global__ void vq_final(const float* __restrict__ ws, float* __restrict__ out) {
    int t = threadIdx.x;   // 128 threads
    if (t == 0) out[OFF_LOSS] = 0.25f * (ws[0] / (float)((size_t)NROWS * DIM));
    int c = ((const int*)ws)[64 + t];
    float p = (float)c / (float)NROWS;
    float v = p * logf(p + 1e-10f);
    #pragma unroll
    for (int off = 32; off; off >>= 1) v += __shfl_down(v, off);
    __shared__ float red[2];
    if ((t & 63) == 0) red[t >> 6] = v;
    __syncthreads();
    if (t == 0) out[OFF_PERP] = expf(-(red[0] + red[1]));
}

extern "C" void kernel_launch(void* const* d_in, const int* in_sizes, int n_in,
                              void* d_out, int out_size, void* d_ws, size_t ws_size,
                              hipStream_t stream) {
    const float* X = (const float*)d_in[0];   // [64,2048,256] fp32
    const float* E = (const float*)d_in[1];   // [128,256] fp32
    float* out = (float*)d_out;
    float* ws  = (float*)d_ws;                // needs >= 1536 bytes

    vq_init <<<NUM_K, 64, 0, stream>>>(E, ws);
    vq_main <<<GRID, BLOCK, 0, stream>>>(X, E, ws, out);
    vq_final<<<1, 128, 0, stream>>>(ws, out);
}